// Round 2
// baseline (796.247 us; speedup 1.0000x reference)
//
#include <hip/hip_runtime.h>

typedef unsigned short ushort_t;
typedef unsigned int   u32;
typedef __attribute__((ext_vector_type(8))) short bf16x8;
typedef __attribute__((ext_vector_type(4))) float f32x4;

#define NNODES 100000
#define DIM    256
#define NEDGE  300000
#define KTOT   512          // virtual K = [agg | xin]
#define KSTEPS 16           // BK = 32
#define BROWS  256          // rows per block (8 row-groups x 32 rows)
#define WCT    8            // col-tiles per wave: N split across 2 waves
#define SLICE  16384        // ushorts per 32-k slice: 2 planes x 256 n x 32 k
// slice layout (ushort units): plane*8192 + ct*512 + quad*128 + nn*8 + j
//   => chunk c = plane*1024 + ct*64 + (quad*16 + nn); 16B chunks, lane-linear

// ================= CSR build (counting sort by dst) =================

__global__ void count_kernel(const int* __restrict__ dst, int* __restrict__ cnt, int E) {
    int e = blockIdx.x * blockDim.x + threadIdx.x;
    if (e < E) atomicAdd(&cnt[dst[e]], 1);
}

__global__ void scan1(const int* __restrict__ cnt, int* __restrict__ partial, int n) {
    __shared__ int s[256];
    int i = blockIdx.x * 256 + threadIdx.x;
    s[threadIdx.x] = (i < n) ? cnt[i] : 0;
    __syncthreads();
    for (int off = 128; off > 0; off >>= 1) {
        if (threadIdx.x < off) s[threadIdx.x] += s[threadIdx.x + off];
        __syncthreads();
    }
    if (threadIdx.x == 0) partial[blockIdx.x] = s[0];
}

__global__ void scan2(int* __restrict__ partial, int nb) {
    __shared__ int s[512];
    int t = threadIdx.x;
    int orig = (t < nb) ? partial[t] : 0;
    s[t] = orig;
    __syncthreads();
    for (int off = 1; off < 512; off <<= 1) {
        int v = (t >= off) ? s[t - off] : 0;
        __syncthreads();
        s[t] += v;
        __syncthreads();
    }
    if (t < nb) partial[t] = s[t] - orig;  // exclusive
}

__global__ void scan3(const int* __restrict__ cnt, const int* __restrict__ partial,
                      int* __restrict__ row_start, int n) {
    __shared__ int s[256];
    int i = blockIdx.x * 256 + threadIdx.x;
    int v = (i < n) ? cnt[i] : 0;
    s[threadIdx.x] = v;
    __syncthreads();
    for (int off = 1; off < 256; off <<= 1) {
        int t = (threadIdx.x >= off) ? s[threadIdx.x - off] : 0;
        __syncthreads();
        s[threadIdx.x] += t;
        __syncthreads();
    }
    if (i < n) row_start[i] = partial[blockIdx.x] + s[threadIdx.x] - v;
}

__global__ void fill_csr(const int* __restrict__ src, const int* __restrict__ dst,
                         const int* __restrict__ row_start, int* __restrict__ cursor,
                         int* __restrict__ esrc, int E) {
    int e = blockIdx.x * blockDim.x + threadIdx.x;
    if (e < E) {
        int d = dst[e];
        int pos = row_start[d] + atomicAdd(&cursor[d], 1);
        esrc[pos] = src[e];
    }
}

// ================= aggregation: one wave per node =================
__global__ __launch_bounds__(256) void aggregate(
    const int* __restrict__ esrc, const int* __restrict__ row_start,
    const int* __restrict__ cnt, const float* __restrict__ x, float* __restrict__ agg)
{
    int node = (blockIdx.x * blockDim.x + threadIdx.x) >> 6;
    int lane = threadIdx.x & 63;
    if (node >= NNODES) return;
    int start = row_start[node];
    int c = cnt[node];
    float4 acc = make_float4(0.f, 0.f, 0.f, 0.f);
    for (int i = 0; i < c; i++) {
        int s = esrc[start + i];
        float4 v = ((const float4*)(x + (size_t)s * DIM))[lane];
        acc.x += v.x; acc.y += v.y; acc.z += v.z; acc.w += v.w;
    }
    float inv = (c > 0) ? 1.0f / (float)c : 0.0f;
    ((float4*)(agg + (size_t)node * DIM))[lane] =
        make_float4(acc.x * inv, acc.y * inv, acc.z * inv, acc.w * inv);
}

// ========== weight split + swizzle into MFMA-fragment/LDS-linear order ==========
__global__ void conv_weights(const float* __restrict__ Wl, const float* __restrict__ Wr,
                             ushort_t* __restrict__ Bsw) {
    int idx = blockIdx.x * 256 + threadIdx.x;      // n*512 + k
    if (idx >= 256 * KTOT) return;
    int n = idx >> 9, k = idx & 511;
    float v = (k < DIM) ? Wl[n * DIM + k] : Wr[n * DIM + (k - DIM)];
    unsigned u = __float_as_uint(v);
    unsigned hb = u & 0xFFFF0000u;
    float lo = v - __uint_as_float(hb);
    int ks = k >> 5, q = (k >> 3) & 3, j = k & 7;
    int ct = n >> 4, nn = n & 15;
    int base = ks * SLICE + ct * 512 + q * 128 + nn * 8 + j;
    Bsw[base]        = (ushort_t)(u >> 16);                      // hi plane
    Bsw[base + 8192] = (ushort_t)(__float_as_uint(lo) >> 16);    // lo plane
}

// ================= helpers =================

// Async direct global->LDS staging of one 32 KB slice by a 1024-thread block.
// 2048 chunks of 16 B; each lane does 2 DMA instructions (vmcnt group of 2).
// LDS dest is wave-uniform base + lane*16 (HW rule); layout is lane-linear.
__device__ __forceinline__ void stage_b_async(const ushort_t* __restrict__ slice,
                                              ushort_t* buf, int tid) {
    const int wave = tid >> 6;
    #pragma unroll
    for (int i = 0; i < 2; i++) {
        const int c  = tid + i * 1024;           // per-lane 16B chunk index
        const int cb = wave * 64 + i * 1024;     // wave-uniform base chunk
        __builtin_amdgcn_global_load_lds(
            (const __attribute__((address_space(1))) u32*)(slice + (size_t)c * 8),
            (__attribute__((address_space(3))) u32*)(buf + cb * 8),
            16, 0, 0);
    }
}

__device__ __forceinline__ void load_a(const float* __restrict__ base, int row0, int row1,
                                       int kk, int M, float* va /*16 floats*/) {
    if (row0 < M) {
        *(float4*)(va + 0) = *(const float4*)(base + (size_t)row0 * DIM + kk);
        *(float4*)(va + 4) = *(const float4*)(base + (size_t)row0 * DIM + kk + 4);
    } else {
        *(float4*)(va + 0) = make_float4(0.f, 0.f, 0.f, 0.f);
        *(float4*)(va + 4) = make_float4(0.f, 0.f, 0.f, 0.f);
    }
    if (row1 < M) {
        *(float4*)(va + 8)  = *(const float4*)(base + (size_t)row1 * DIM + kk);
        *(float4*)(va + 12) = *(const float4*)(base + (size_t)row1 * DIM + kk + 4);
    } else {
        *(float4*)(va + 8)  = make_float4(0.f, 0.f, 0.f, 0.f);
        *(float4*)(va + 12) = make_float4(0.f, 0.f, 0.f, 0.f);
    }
}

__device__ __forceinline__ void split8(const float* __restrict__ a, bf16x8& h, bf16x8& l) {
    #pragma unroll
    for (int i = 0; i < 8; i++) {
        float x = a[i];
        unsigned u = __float_as_uint(x);
        unsigned hb = u & 0xFFFF0000u;
        h[i] = (short)(u >> 16);
        float lo = x - __uint_as_float(hb);
        l[i] = (short)(__float_as_uint(lo) >> 16);
    }
}

// ================= MFMA GEMM: out = [agg|xin] @ B^T + bias (split-bf16, fp32 acc) ===============
// 1024 threads / 16 waves. Wave w: row-group w>>1 (32 rows), col-group w&1 (8 col-tiles).
// B prefetch is 2-deep (tri-buffered LDS, 96 KB) so the per-iteration barrier uses a
// COUNTED wait (vmcnt(2): next-next B slice's 2 DMAs stay in flight across the barrier)
// instead of a full drain — the m201/T3+T4 pattern. A prefetch is 1-deep, issued BEFORE
// the B stage so it is always older than the surviving vmcnt group.
__global__ __launch_bounds__(1024, 4) void sage_gemm_mfma(
    const float* __restrict__ agg, const float* __restrict__ xin,
    const ushort_t* __restrict__ Bsw,
    const float* __restrict__ bias, float* __restrict__ out, int M, int do_relu)
{
    __shared__ __align__(16) ushort_t Bs[3][SLICE];   // 96 KB tri-buffer

    const int tid  = threadIdx.x;
    const int lane = tid & 63;
    const int wave = tid >> 6;          // 0..15
    const int lrow = lane & 15;
    const int quad = lane >> 4;
    const int rg   = wave >> 1;         // row-group 0..7
    const int cg   = wave & 1;          // col-group 0..1

    const int rowbase = blockIdx.x * BROWS + rg * 32;
    const int arow0 = rowbase + lrow;
    const int arow1 = rowbase + 16 + lrow;
    const int kq    = quad * 8;
    const int ctbase = cg * WCT;        // 0 or 8

    f32x4 acc[2][WCT];
    #pragma unroll
    for (int i = 0; i < 2; i++)
        #pragma unroll
        for (int j = 0; j < WCT; j++)
            acc[i][j] = (f32x4){0.f, 0.f, 0.f, 0.f};

    float aN[16];
    // prologue: B[0], A[0], B[1]  (issue order matters for the counted waits)
    stage_b_async(Bsw, &Bs[0][0], tid);
    load_a(agg, arow0, arow1, kq, M, aN);
    stage_b_async(Bsw + SLICE, &Bs[1][0], tid);

    #pragma unroll
    for (int ks = 0; ks < KSTEPS; ks++) {
        // need: B[ks] in LDS + A[ks] in regs. Outstanding (newest first):
        // B[ks+1] (2 DMA), A[ks] (4 loads) -> vmcnt(2) completes A[ks] and all
        // older (incl. B[ks]) while B[ks+1] keeps flying across the barrier.
        __builtin_amdgcn_sched_barrier(0);
        if (ks == KSTEPS - 1) {
            asm volatile("s_waitcnt vmcnt(0)" ::: "memory");   // no newer loads exist
        } else {
            asm volatile("s_waitcnt vmcnt(2)" ::: "memory");
        }
        __builtin_amdgcn_s_barrier();
        __builtin_amdgcn_sched_barrier(0);

        bf16x8 ah0, al0, ah1, al1;
        split8(aN + 0, ah0, al0);
        split8(aN + 8, ah1, al1);

        if (ks + 1 < KSTEPS) {           // A[ks+1] (issued BEFORE B-stage: older group)
            const int ks1 = ks + 1;
            const float* base = (ks1 < 8) ? agg : xin;
            const int kk = ((ks1 < 8) ? ks1 * 32 : (ks1 - 8) * 32) + kq;
            load_a(base, arow0, arow1, kk, M, aN);
        }
        if (ks + 2 < KSTEPS)             // B[ks+2] -> buffer being freed this iter's +3
            stage_b_async(Bsw + (size_t)(ks + 2) * SLICE, &Bs[(ks + 2) % 3][0], tid);

        const ushort_t* bp = &Bs[ks % 3][ctbase * 512 + lane * 8];
        #pragma unroll
        for (int j = 0; j < WCT; j++) {
            const bf16x8 bh = *(const bf16x8*)(bp + j * 512);
            const bf16x8 bl = *(const bf16x8*)(bp + 8192 + j * 512);
            acc[0][j] = __builtin_amdgcn_mfma_f32_16x16x32_bf16(ah0, bh, acc[0][j], 0, 0, 0);
            acc[1][j] = __builtin_amdgcn_mfma_f32_16x16x32_bf16(ah1, bh, acc[1][j], 0, 0, 0);
            acc[0][j] = __builtin_amdgcn_mfma_f32_16x16x32_bf16(al0, bh, acc[0][j], 0, 0, 0);
            acc[1][j] = __builtin_amdgcn_mfma_f32_16x16x32_bf16(al1, bh, acc[1][j], 0, 0, 0);
            acc[0][j] = __builtin_amdgcn_mfma_f32_16x16x32_bf16(ah0, bl, acc[0][j], 0, 0, 0);
            acc[1][j] = __builtin_amdgcn_mfma_f32_16x16x32_bf16(ah1, bl, acc[1][j], 0, 0, 0);
        }
    }

    // ---- epilogue: bias + optional relu; C layout: col=lane&15, row=quad*4+reg ----
    #pragma unroll
    for (int j = 0; j < WCT; j++) {
        const int col = (ctbase + j) * 16 + lrow;
        const float bv = bias[col];
        #pragma unroll
        for (int rt = 0; rt < 2; rt++) {
            const int row = rowbase + rt * 16 + quad * 4;
            #pragma unroll
            for (int r = 0; r < 4; r++) {
                if (row + r < M) {
                    float v = acc[rt][j][r] + bv;
                    if (do_relu) v = fmaxf(v, 0.f);
                    out[(size_t)(row + r) * DIM + col] = v;
                }
            }
        }
    }
}

extern "C" void kernel_launch(void* const* d_in, const int* in_sizes, int n_in,
                              void* d_out, int out_size, void* d_ws, size_t ws_size,
                              hipStream_t stream) {
    const int*   edge = (const int*)d_in[0];
    const int*   src  = edge;
    const int*   dst  = edge + NEDGE;
    const float* x    = (const float*)d_in[1];
    const float* Wl1  = (const float*)d_in[2];
    const float* Wr1  = (const float*)d_in[3];
    const float* b1   = (const float*)d_in[4];
    const float* Wl2  = (const float*)d_in[5];
    const float* Wr2  = (const float*)d_in[6];
    const float* b2   = (const float*)d_in[7];
    const float* Wl3  = (const float*)d_in[8];
    const float* Wr3  = (const float*)d_in[9];
    const float* b3   = (const float*)d_in[10];

    const size_t feat = (size_t)NNODES * DIM;
    float*    agg       = (float*)d_ws;
    float*    h2        = agg + feat;
    int*      cnt       = (int*)(h2 + feat);
    int*      row_start = cnt + NNODES;
    int*      cursor    = row_start + NNODES;
    int*      partial   = cursor + NNODES;            // 512
    int*      esrc      = partial + 512;              // NEDGE
    ushort_t* Bsw       = (ushort_t*)(esrc + NEDGE);  // KSTEPS*SLICE ushorts (512 KB)
    float*    h1        = (float*)d_out;   // layer-1 out in d_out; rewritten by layer 3

    const int nScanBlocks = (NNODES + 255) / 256;

    // ---- CSR build (edge structure shared by all 3 layers) ----
    hipMemsetAsync(cnt, 0, NNODES * sizeof(int), stream);
    hipMemsetAsync(cursor, 0, NNODES * sizeof(int), stream);
    count_kernel<<<(NEDGE + 255) / 256, 256, 0, stream>>>(dst, cnt, NEDGE);
    scan1<<<nScanBlocks, 256, 0, stream>>>(cnt, partial, NNODES);
    scan2<<<1, 512, 0, stream>>>(partial, nScanBlocks);
    scan3<<<nScanBlocks, 256, 0, stream>>>(cnt, partial, row_start, NNODES);
    fill_csr<<<(NEDGE + 255) / 256, 256, 0, stream>>>(src, dst, row_start, cursor, esrc, NEDGE);

    const int aggBlocks  = (NNODES * 64 + 255) / 256;
    const int gemmBlocks = (NNODES + BROWS - 1) / BROWS;
    const int convBlocks = (256 * KTOT + 255) / 256;

    // ---- layer 1 ----
    conv_weights<<<convBlocks, 256, 0, stream>>>(Wl1, Wr1, Bsw);
    aggregate<<<aggBlocks, 256, 0, stream>>>(esrc, row_start, cnt, x, agg);
    sage_gemm_mfma<<<gemmBlocks, 1024, 0, stream>>>(agg, x, Bsw, b1, h1, NNODES, 1);

    // ---- layer 2 ----
    conv_weights<<<convBlocks, 256, 0, stream>>>(Wl2, Wr2, Bsw);
    aggregate<<<aggBlocks, 256, 0, stream>>>(esrc, row_start, cnt, h1, agg);
    sage_gemm_mfma<<<gemmBlocks, 1024, 0, stream>>>(agg, h1, Bsw, b2, h2, NNODES, 1);

    // ---- layer 3 ----
    conv_weights<<<convBlocks, 256, 0, stream>>>(Wl3, Wr3, Bsw);
    aggregate<<<aggBlocks, 256, 0, stream>>>(esrc, row_start, cnt, h2, agg);
    sage_gemm_mfma<<<gemmBlocks, 1024, 0, stream>>>(agg, h2, Bsw, b3, (float*)d_out, NNODES, 0);
}

// Round 3
// 770.831 us; speedup vs baseline: 1.0330x; 1.0330x over previous
//
#include <hip/hip_runtime.h>

typedef unsigned short ushort_t;
typedef unsigned int   u32;
typedef __attribute__((ext_vector_type(8))) short bf16x8;
typedef __attribute__((ext_vector_type(4))) float f32x4;

#define NNODES 100000
#define DIM    256
#define NEDGE  300000
#define KTOT   512          // virtual K = [agg | xin]
#define KSTEPS 16           // BK = 32
#define BROWS  128          // rows per block (4 row-groups x 32 rows)
#define WCT    8            // col-tiles per wave: N split across 2 waves
#define SLICE  16384        // ushorts per 32-k slice: 2 planes x 256 n x 32 k
// slice layout (ushort units): plane*8192 + ct*512 + q*128 + nn*8 + j
// k-slot mapping (A and B must agree; MFMA sums over slots so any bijection works):
//   slot (q,j) <-> within-slice k5 = 4*q + (j&3) + 16*(j>>2)
// This makes each A-load instruction cover 16 rows x contiguous 64B.

// ================= CSR build (counting sort by dst) =================

__global__ void count_kernel(const int* __restrict__ dst, int* __restrict__ cnt, int E) {
    int e = blockIdx.x * blockDim.x + threadIdx.x;
    if (e < E) atomicAdd(&cnt[dst[e]], 1);
}

__global__ void scan1(const int* __restrict__ cnt, int* __restrict__ partial, int n) {
    __shared__ int s[256];
    int i = blockIdx.x * 256 + threadIdx.x;
    s[threadIdx.x] = (i < n) ? cnt[i] : 0;
    __syncthreads();
    for (int off = 128; off > 0; off >>= 1) {
        if (threadIdx.x < off) s[threadIdx.x] += s[threadIdx.x + off];
        __syncthreads();
    }
    if (threadIdx.x == 0) partial[blockIdx.x] = s[0];
}

__global__ void scan2(int* __restrict__ partial, int nb) {
    __shared__ int s[512];
    int t = threadIdx.x;
    int orig = (t < nb) ? partial[t] : 0;
    s[t] = orig;
    __syncthreads();
    for (int off = 1; off < 512; off <<= 1) {
        int v = (t >= off) ? s[t - off] : 0;
        __syncthreads();
        s[t] += v;
        __syncthreads();
    }
    if (t < nb) partial[t] = s[t] - orig;  // exclusive
}

__global__ void scan3(const int* __restrict__ cnt, const int* __restrict__ partial,
                      int* __restrict__ row_start, int n) {
    __shared__ int s[256];
    int i = blockIdx.x * 256 + threadIdx.x;
    int v = (i < n) ? cnt[i] : 0;
    s[threadIdx.x] = v;
    __syncthreads();
    for (int off = 1; off < 256; off <<= 1) {
        int t = (threadIdx.x >= off) ? s[threadIdx.x - off] : 0;
        __syncthreads();
        s[threadIdx.x] += t;
        __syncthreads();
    }
    if (i < n) row_start[i] = partial[blockIdx.x] + s[threadIdx.x] - v;
}

__global__ void fill_csr(const int* __restrict__ src, const int* __restrict__ dst,
                         const int* __restrict__ row_start, int* __restrict__ cursor,
                         int* __restrict__ esrc, int E) {
    int e = blockIdx.x * blockDim.x + threadIdx.x;
    if (e < E) {
        int d = dst[e];
        int pos = row_start[d] + atomicAdd(&cursor[d], 1);
        esrc[pos] = src[e];
    }
}

// ================= aggregation: one wave per node =================
__global__ __launch_bounds__(256) void aggregate(
    const int* __restrict__ esrc, const int* __restrict__ row_start,
    const int* __restrict__ cnt, const float* __restrict__ x, float* __restrict__ agg)
{
    int node = (blockIdx.x * blockDim.x + threadIdx.x) >> 6;
    int lane = threadIdx.x & 63;
    if (node >= NNODES) return;
    int start = row_start[node];
    int c = cnt[node];
    float4 acc = make_float4(0.f, 0.f, 0.f, 0.f);
    for (int i = 0; i < c; i++) {
        int s = esrc[start + i];
        float4 v = ((const float4*)(x + (size_t)s * DIM))[lane];
        acc.x += v.x; acc.y += v.y; acc.z += v.z; acc.w += v.w;
    }
    float inv = (c > 0) ? 1.0f / (float)c : 0.0f;
    ((float4*)(agg + (size_t)node * DIM))[lane] =
        make_float4(acc.x * inv, acc.y * inv, acc.z * inv, acc.w * inv);
}

// ========== weight split + swizzle into MFMA-fragment/LDS-linear order ==========
__global__ void conv_weights(const float* __restrict__ Wl, const float* __restrict__ Wr,
                             ushort_t* __restrict__ Bsw) {
    int idx = blockIdx.x * 256 + threadIdx.x;      // n*512 + k
    if (idx >= 256 * KTOT) return;
    int n = idx >> 9, k = idx & 511;
    float v = (k < DIM) ? Wl[n * DIM + k] : Wr[n * DIM + (k - DIM)];
    unsigned u = __float_as_uint(v);
    unsigned hb = u & 0xFFFF0000u;
    float lo = v - __uint_as_float(hb);
    int ks = k >> 5;
    int k5 = k & 31;
    int q  = (k5 >> 2) & 3;                 // slot mapping: k5 = 4q + (j&3) + 16*(j>>2)
    int j  = (k5 & 3) | ((k5 >> 4) << 2);
    int ct = n >> 4, nn = n & 15;
    int base = ks * SLICE + ct * 512 + q * 128 + nn * 8 + j;
    Bsw[base]        = (ushort_t)(u >> 16);                      // hi plane
    Bsw[base + 8192] = (ushort_t)(__float_as_uint(lo) >> 16);    // lo plane
}

// ================= helpers =================

// Async direct global->LDS staging of one 32 KB slice by a 512-thread block.
// 2048 chunks of 16 B; 4 DMA instructions per thread (vmcnt group of 4 per wave).
__device__ __forceinline__ void stage_b_async(const ushort_t* __restrict__ slice,
                                              ushort_t* buf, int tid) {
    const int wave = tid >> 6;
    #pragma unroll
    for (int i = 0; i < 4; i++) {
        const int c  = tid + i * 512;            // per-lane 16B chunk index
        const int cb = wave * 64 + i * 512;      // wave-uniform base chunk
        __builtin_amdgcn_global_load_lds(
            (const __attribute__((address_space(1))) u32*)(slice + (size_t)c * 8),
            (__attribute__((address_space(3))) u32*)(buf + cb * 8),
            16, 0, 0);
    }
}

// Unconditional (clamped) A loads: every wave issues exactly 4 VMEM instructions,
// keeping per-wave vmcnt counts uniform (required for the counted barrier wait).
// Slot mapping: va[0..3] = A[row][kk+4q .. +3], va[4..7] = A[row][kk+16+4q .. +3].
__device__ __forceinline__ void load_a(const float* __restrict__ base, int row0, int row1,
                                       int kk, int q, int M, float* va /*16 floats*/) {
    const int r0 = (row0 < M) ? row0 : (M - 1);
    const int r1 = (row1 < M) ? row1 : (M - 1);
    const float* p0 = base + (size_t)r0 * DIM + kk + 4 * q;
    const float* p1 = base + (size_t)r1 * DIM + kk + 4 * q;
    *(float4*)(va + 0)  = *(const float4*)(p0);
    *(float4*)(va + 4)  = *(const float4*)(p0 + 16);
    *(float4*)(va + 8)  = *(const float4*)(p1);
    *(float4*)(va + 12) = *(const float4*)(p1 + 16);
}

__device__ __forceinline__ void split8(const float* __restrict__ a, bf16x8& h, bf16x8& l) {
    #pragma unroll
    for (int i = 0; i < 8; i++) {
        float x = a[i];
        unsigned u = __float_as_uint(x);
        unsigned hb = u & 0xFFFF0000u;
        h[i] = (short)(u >> 16);
        float lo = x - __uint_as_float(hb);
        l[i] = (short)(__float_as_uint(lo) >> 16);
    }
}

// ================= MFMA GEMM: out = [agg|xin] @ B^T + bias (split-bf16, fp32 acc) ===============
// 512 threads / 8 waves; double-buffered LDS (64 KB) -> 2 independent blocks/CU.
// Counted-vmcnt pipeline (T3/T4 minimum form):
//   issue order per iter j: [vmcnt(4); s_barrier] ; stage B[j+1] ; split A[j] ; load A[j+2] ; MFMA
//   At each barrier the 4 newest VMEM ops (A[j+2]) stay in flight; B[j] (issued early in
//   iter j-1, one full phase ago) and A[j] (issued two phases ago) are forced complete.
//   Last iter uses vmcnt(0) (B[15] is then the newest outstanding group).
__global__ __launch_bounds__(512, 4) void sage_gemm_mfma(
    const float* __restrict__ agg, const float* __restrict__ xin,
    const ushort_t* __restrict__ Bsw,
    const float* __restrict__ bias, float* __restrict__ out, int M, int do_relu)
{
    __shared__ __align__(16) ushort_t Bs[2][SLICE];

    const int tid  = threadIdx.x;
    const int lane = tid & 63;
    const int wave = tid >> 6;          // 0..7
    const int lrow = lane & 15;
    const int quad = lane >> 4;
    const int rg   = wave >> 1;         // row-group 0..3
    const int cg   = wave & 1;          // col-group 0..1

    const int rowbase = blockIdx.x * BROWS + rg * 32;
    const int arow0 = rowbase + lrow;
    const int arow1 = rowbase + 16 + lrow;
    const int ctbase = cg * WCT;        // 0 or 8

    f32x4 acc[2][WCT];
    #pragma unroll
    for (int i = 0; i < 2; i++)
        #pragma unroll
        for (int j = 0; j < WCT; j++)
            acc[i][j] = (f32x4){0.f, 0.f, 0.f, 0.f};

    float a0[16], a1[16];               // A[j] lives in (j&1 ? a1 : a0)

    // prologue (issue order matters): B[0], A[0], A[1]
    stage_b_async(Bsw, &Bs[0][0], tid);
    load_a(agg, arow0, arow1, 0, quad, M, a0);
    load_a(agg, arow0, arow1, 32, quad, M, a1);

    #pragma unroll
    for (int ks = 0; ks < KSTEPS; ks++) {
        __builtin_amdgcn_sched_barrier(0);
        if (ks == KSTEPS - 1) {
            asm volatile("s_waitcnt vmcnt(0)" ::: "memory");
        } else {
            asm volatile("s_waitcnt vmcnt(4)" ::: "memory");
        }
        __builtin_amdgcn_s_barrier();
        __builtin_amdgcn_sched_barrier(0);

        // stage B[ks+1] early: gets the full compute phase to land (L2-resident source)
        if (ks + 1 < KSTEPS)
            stage_b_async(Bsw + (size_t)(ks + 1) * SLICE, &Bs[(ks + 1) & 1][0], tid);
        __builtin_amdgcn_sched_barrier(0);

        float* curA = (ks & 1) ? a1 : a0;

        bf16x8 ah0, al0, ah1, al1;
        split8(curA + 0, ah0, al0);
        split8(curA + 8, ah1, al1);

        // A[ks+2] reuses the buffer just consumed; issued after B so it is the
        // newest vmcnt group (the 4 that fly across the next two barriers).
        if (ks + 2 < KSTEPS) {
            const int ks2 = ks + 2;
            const float* basep = (ks2 < 8) ? agg : xin;
            const int kk = (ks2 < 8) ? ks2 * 32 : (ks2 - 8) * 32;
            load_a(basep, arow0, arow1, kk, quad, M, curA);
        }

        const ushort_t* bp = &Bs[ks & 1][ctbase * 512 + lane * 8];
        #pragma unroll
        for (int j = 0; j < WCT; j++) {
            const bf16x8 bh = *(const bf16x8*)(bp + j * 512);
            const bf16x8 bl = *(const bf16x8*)(bp + 8192 + j * 512);
            acc[0][j] = __builtin_amdgcn_mfma_f32_16x16x32_bf16(ah0, bh, acc[0][j], 0, 0, 0);
            acc[1][j] = __builtin_amdgcn_mfma_f32_16x16x32_bf16(ah1, bh, acc[1][j], 0, 0, 0);
            acc[0][j] = __builtin_amdgcn_mfma_f32_16x16x32_bf16(al0, bh, acc[0][j], 0, 0, 0);
            acc[1][j] = __builtin_amdgcn_mfma_f32_16x16x32_bf16(al1, bh, acc[1][j], 0, 0, 0);
            acc[0][j] = __builtin_amdgcn_mfma_f32_16x16x32_bf16(ah0, bl, acc[0][j], 0, 0, 0);
            acc[1][j] = __builtin_amdgcn_mfma_f32_16x16x32_bf16(ah1, bl, acc[1][j], 0, 0, 0);
        }
    }

    // ---- epilogue: bias + optional relu; C layout: col=lane&15, row=quad*4+reg ----
    #pragma unroll
    for (int j = 0; j < WCT; j++) {
        const int col = (ctbase + j) * 16 + lrow;
        const float bv = bias[col];
        #pragma unroll
        for (int rt = 0; rt < 2; rt++) {
            const int row = rowbase + rt * 16 + quad * 4;
            #pragma unroll
            for (int r = 0; r < 4; r++) {
                if (row + r < M) {
                    float v = acc[rt][j][r] + bv;
                    if (do_relu) v = fmaxf(v, 0.f);
                    out[(size_t)(row + r) * DIM + col] = v;
                }
            }
        }
    }
}

extern "C" void kernel_launch(void* const* d_in, const int* in_sizes, int n_in,
                              void* d_out, int out_size, void* d_ws, size_t ws_size,
                              hipStream_t stream) {
    const int*   edge = (const int*)d_in[0];
    const int*   src  = edge;
    const int*   dst  = edge + NEDGE;
    const float* x    = (const float*)d_in[1];
    const float* Wl1  = (const float*)d_in[2];
    const float* Wr1  = (const float*)d_in[3];
    const float* b1   = (const float*)d_in[4];
    const float* Wl2  = (const float*)d_in[5];
    const float* Wr2  = (const float*)d_in[6];
    const float* b2   = (const float*)d_in[7];
    const float* Wl3  = (const float*)d_in[8];
    const float* Wr3  = (const float*)d_in[9];
    const float* b3   = (const float*)d_in[10];

    const size_t feat = (size_t)NNODES * DIM;
    float*    agg       = (float*)d_ws;
    float*    h2        = agg + feat;
    int*      cnt       = (int*)(h2 + feat);
    int*      row_start = cnt + NNODES;
    int*      cursor    = row_start + NNODES;
    int*      partial   = cursor + NNODES;            // 512
    int*      esrc      = partial + 512;              // NEDGE
    ushort_t* Bsw       = (ushort_t*)(esrc + NEDGE);  // KSTEPS*SLICE ushorts (512 KB)
    float*    h1        = (float*)d_out;   // layer-1 out in d_out; rewritten by layer 3

    const int nScanBlocks = (NNODES + 255) / 256;

    // ---- CSR build (edge structure shared by all 3 layers) ----
    hipMemsetAsync(cnt, 0, NNODES * sizeof(int), stream);
    hipMemsetAsync(cursor, 0, NNODES * sizeof(int), stream);
    count_kernel<<<(NEDGE + 255) / 256, 256, 0, stream>>>(dst, cnt, NEDGE);
    scan1<<<nScanBlocks, 256, 0, stream>>>(cnt, partial, NNODES);
    scan2<<<1, 512, 0, stream>>>(partial, nScanBlocks);
    scan3<<<nScanBlocks, 256, 0, stream>>>(cnt, partial, row_start, NNODES);
    fill_csr<<<(NEDGE + 255) / 256, 256, 0, stream>>>(src, dst, row_start, cursor, esrc, NEDGE);

    const int aggBlocks  = (NNODES * 64 + 255) / 256;
    const int gemmBlocks = (NNODES + BROWS - 1) / BROWS;
    const int convBlocks = (256 * KTOT + 255) / 256;

    // ---- layer 1 ----
    conv_weights<<<convBlocks, 256, 0, stream>>>(Wl1, Wr1, Bsw);
    aggregate<<<aggBlocks, 256, 0, stream>>>(esrc, row_start, cnt, x, agg);
    sage_gemm_mfma<<<gemmBlocks, 512, 0, stream>>>(agg, x, Bsw, b1, h1, NNODES, 1);

    // ---- layer 2 ----
    conv_weights<<<convBlocks, 256, 0, stream>>>(Wl2, Wr2, Bsw);
    aggregate<<<aggBlocks, 256, 0, stream>>>(esrc, row_start, cnt, h1, agg);
    sage_gemm_mfma<<<gemmBlocks, 512, 0, stream>>>(agg, h1, Bsw, b2, h2, NNODES, 1);

    // ---- layer 3 ----
    conv_weights<<<convBlocks, 256, 0, stream>>>(Wl3, Wr3, Bsw);
    aggregate<<<aggBlocks, 256, 0, stream>>>(esrc, row_start, cnt, h2, agg);
    sage_gemm_mfma<<<gemmBlocks, 512, 0, stream>>>(agg, h2, Bsw, b3, (float*)d_out, NNODES, 0);
}

// Round 4
// 617.648 us; speedup vs baseline: 1.2892x; 1.2480x over previous
//
#include <hip/hip_runtime.h>

typedef unsigned short ushort_t;
typedef unsigned int   u32;
typedef __attribute__((ext_vector_type(8))) short bf16x8;
typedef __attribute__((ext_vector_type(4))) float f32x4;

#define NNODES 100000
#define DIM    256
#define NEDGE  300000
#define KSTEPS 16           // BK = 32 over virtual K = [agg | xin] = 512
#define BROWS  128          // rows per block (4 row-groups x 32 rows)
#define WCT    8            // col-tiles per wave (N split across 2 waves)
#define SLICE  16384        // ushorts per 32-k B slice: 2 planes x 256 n x 32 k
// B slice layout (ushort units): plane*8192 + ct*512 + q*128 + nn*8 + j  (round-1 mapping)
// A tensors (x2 / h / agg2) are split-bf16 planes: row = [256 hi ushorts | 256 lo ushorts]
#define MFMA16 __builtin_amdgcn_mfma_f32_16x16x32_bf16

// ================= CSR build (counting sort by dst) =================

__global__ void count_kernel(const int* __restrict__ dst, int* __restrict__ cnt, int E) {
    int e = blockIdx.x * blockDim.x + threadIdx.x;
    if (e < E) atomicAdd(&cnt[dst[e]], 1);
}

__global__ void scan1(const int* __restrict__ cnt, int* __restrict__ partial, int n) {
    __shared__ int s[256];
    int i = blockIdx.x * 256 + threadIdx.x;
    s[threadIdx.x] = (i < n) ? cnt[i] : 0;
    __syncthreads();
    for (int off = 128; off > 0; off >>= 1) {
        if (threadIdx.x < off) s[threadIdx.x] += s[threadIdx.x + off];
        __syncthreads();
    }
    if (threadIdx.x == 0) partial[blockIdx.x] = s[0];
}

__global__ void scan2(int* __restrict__ partial, int nb) {
    __shared__ int s[512];
    int t = threadIdx.x;
    int orig = (t < nb) ? partial[t] : 0;
    s[t] = orig;
    __syncthreads();
    for (int off = 1; off < 512; off <<= 1) {
        int v = (t >= off) ? s[t - off] : 0;
        __syncthreads();
        s[t] += v;
        __syncthreads();
    }
    if (t < nb) partial[t] = s[t] - orig;  // exclusive
}

__global__ void scan3(const int* __restrict__ cnt, const int* __restrict__ partial,
                      int* __restrict__ row_start, int n) {
    __shared__ int s[256];
    int i = blockIdx.x * 256 + threadIdx.x;
    int v = (i < n) ? cnt[i] : 0;
    s[threadIdx.x] = v;
    __syncthreads();
    for (int off = 1; off < 256; off <<= 1) {
        int t = (threadIdx.x >= off) ? s[threadIdx.x - off] : 0;
        __syncthreads();
        s[threadIdx.x] += t;
        __syncthreads();
    }
    if (i < n) row_start[i] = partial[blockIdx.x] + s[threadIdx.x] - v;
}

__global__ void fill_csr(const int* __restrict__ src, const int* __restrict__ dst,
                         const int* __restrict__ row_start, int* __restrict__ cursor,
                         int* __restrict__ esrc, int E) {
    int e = blockIdx.x * blockDim.x + threadIdx.x;
    if (e < E) {
        int d = dst[e];
        int pos = row_start[d] + atomicAdd(&cursor[d], 1);
        esrc[pos] = src[e];
    }
}

// ================= split helpers =================

__device__ __forceinline__ float bfhi(unsigned u) { return __uint_as_float(u << 16); }
__device__ __forceinline__ float bflo(unsigned u) { return __uint_as_float(u & 0xFFFF0000u); }

// split 4 floats -> packed hi uint2 + lo uint2 (truncating split, identical to old split8)
__device__ __forceinline__ void split4pack(float v0, float v1, float v2, float v3,
                                           uint2& hi, uint2& lo) {
    unsigned u0 = __float_as_uint(v0), u1 = __float_as_uint(v1);
    unsigned u2 = __float_as_uint(v2), u3 = __float_as_uint(v3);
    hi.x = (u0 >> 16) | (u1 & 0xFFFF0000u);
    hi.y = (u2 >> 16) | (u3 & 0xFFFF0000u);
    unsigned w0 = __float_as_uint(v0 - bflo(u0)), w1 = __float_as_uint(v1 - bflo(u1));
    unsigned w2 = __float_as_uint(v2 - bflo(u2)), w3 = __float_as_uint(v3 - bflo(u3));
    lo.x = (w0 >> 16) | (w1 & 0xFFFF0000u);
    lo.y = (w2 >> 16) | (w3 & 0xFFFF0000u);
}

// ================= x -> split-plane form (one-time) =================
__global__ __launch_bounds__(256) void split_x(const float* __restrict__ x,
                                               ushort_t* __restrict__ x2) {
    int idx = blockIdx.x * 256 + threadIdx.x;      // node*64 + lane
    if (idx >= NNODES * 64) return;
    int node = idx >> 6, lane = idx & 63;
    float4 v = ((const float4*)(x + (size_t)node * DIM))[lane];
    uint2 hi, lo;
    split4pack(v.x, v.y, v.z, v.w, hi, lo);
    *(uint2*)(x2 + (size_t)node * 512 + lane * 4)       = hi;
    *(uint2*)(x2 + (size_t)node * 512 + 256 + lane * 4) = lo;
}

// ================= aggregation: one wave per node, split-plane in/out =================
__global__ __launch_bounds__(256) void aggregate2(
    const int* __restrict__ esrc, const int* __restrict__ row_start,
    const int* __restrict__ cnt, const ushort_t* __restrict__ x2,
    ushort_t* __restrict__ agg2)
{
    int node = (blockIdx.x * blockDim.x + threadIdx.x) >> 6;
    int lane = threadIdx.x & 63;
    if (node >= NNODES) return;
    int start = row_start[node];
    int c = cnt[node];
    float a0 = 0.f, a1 = 0.f, a2 = 0.f, a3 = 0.f;
    for (int i = 0; i < c; i++) {
        int s = esrc[start + i];
        const uint2 h = *(const uint2*)(x2 + (size_t)s * 512 + lane * 4);
        const uint2 l = *(const uint2*)(x2 + (size_t)s * 512 + 256 + lane * 4);
        a0 += bfhi(h.x) + bfhi(l.x);
        a1 += bflo(h.x) + bflo(l.x);
        a2 += bfhi(h.y) + bfhi(l.y);
        a3 += bflo(h.y) + bflo(l.y);
    }
    float inv = (c > 0) ? 1.0f / (float)c : 0.0f;
    uint2 hi, lo;
    split4pack(a0 * inv, a1 * inv, a2 * inv, a3 * inv, hi, lo);
    *(uint2*)(agg2 + (size_t)node * 512 + lane * 4)       = hi;
    *(uint2*)(agg2 + (size_t)node * 512 + 256 + lane * 4) = lo;
}

// ========== weight split + swizzle into MFMA-fragment/LDS-linear order (round-1 mapping) ==========
__global__ void conv_weights(const float* __restrict__ Wl, const float* __restrict__ Wr,
                             ushort_t* __restrict__ Bsw) {
    int idx = blockIdx.x * 256 + threadIdx.x;      // n*512 + k
    if (idx >= 256 * 512) return;
    int n = idx >> 9, k = idx & 511;
    float v = (k < DIM) ? Wl[n * DIM + k] : Wr[n * DIM + (k - DIM)];
    unsigned u = __float_as_uint(v);
    float lo = v - bflo(u);
    int ks = k >> 5, q = (k >> 3) & 3, j = k & 7;
    int ct = n >> 4, nn = n & 15;
    int base = ks * SLICE + ct * 512 + q * 128 + nn * 8 + j;
    Bsw[base]        = (ushort_t)(u >> 16);                      // hi plane
    Bsw[base + 8192] = (ushort_t)(__float_as_uint(lo) >> 16);    // lo plane
}

// ================= GEMM helpers =================

// Async direct global->LDS staging of one 32 KB B slice by a 512-thread block.
// 2048 chunks of 16 B; 4 DMA instructions per wave (uniform vmcnt contribution).
__device__ __forceinline__ void stage_b_async(const ushort_t* __restrict__ slice,
                                              ushort_t* buf, int tid) {
    const int wave = tid >> 6;
    #pragma unroll
    for (int i = 0; i < 4; i++) {
        const int c  = tid + i * 512;            // per-lane 16B chunk index
        const int cb = wave * 64 + i * 512;      // wave-uniform base chunk
        __builtin_amdgcn_global_load_lds(
            (const __attribute__((address_space(1))) u32*)(slice + (size_t)c * 8),
            (__attribute__((address_space(3))) u32*)(buf + cb * 8),
            16, 0, 0);
    }
}

// A fragments come pre-split: 4 x 16B loads (row0 hi, row0 lo, row1 hi, row1 lo).
// Rows pre-clamped -> unconditional, uniform vmcnt counts across waves.
__device__ __forceinline__ void load_afrag(const ushort_t* __restrict__ base,
                                           int r0, int r1, int kk, bf16x8* f) {
    const ushort_t* p0 = base + (size_t)r0 * 512 + kk;
    const ushort_t* p1 = base + (size_t)r1 * 512 + kk;
    f[0] = *(const bf16x8*)(p0);
    f[1] = *(const bf16x8*)(p0 + 256);
    f[2] = *(const bf16x8*)(p1);
    f[3] = *(const bf16x8*)(p1 + 256);
}

// ================= MFMA GEMM: out = [agg|xin] @ B^T + bias (split-bf16, fp32 acc) ===============
// 512 threads / 8 waves; double-buffered B in LDS (64 KB) -> 2 independent blocks/CU.
// Counted-vmcnt pipeline: per iter j the VMEM issue order is
//   [vmcnt(4); s_barrier] ; stage B[j+1] (4 DMA) ; MFMA burst (reads fr[j&1]) ; load A[j+2] (4)
// At each barrier the 4 newest ops (A[j+2]) stay in flight; B[j] (staged at the start of
// iter j-1) and A[j] (loaded at the end of iter j-2) are forced complete — each had >= 1
// full MFMA phase to land. A prefetch is 2-deep in bf16 frags (32 VGPR, no f32 buffers,
// no split VALU) so total pressure ~112 < 128 (the round-3 spill is structurally gone).
// out_split: 1 -> write split-plane h (+relu); 0 -> write f32 (final layer).
// NOTE: xin2 and outp may alias (in-place): A-tile rows == block's own output rows, and
// the epilogue runs after all A reads of this block; other blocks never read these rows.
__global__ __launch_bounds__(512, 4) void sage_gemm_mfma(
    const ushort_t* __restrict__ agg2, const ushort_t* __restrict__ xin2,
    const ushort_t* __restrict__ Bsw, const float* __restrict__ bias,
    void* __restrict__ outp, int M, int out_split)
{
    __shared__ __align__(16) ushort_t Bs[2][SLICE];

    const int tid  = threadIdx.x;
    const int lane = tid & 63;
    const int wave = tid >> 6;          // 0..7
    const int lrow = lane & 15;
    const int quad = lane >> 4;
    const int rg   = wave >> 1;         // row-group 0..3
    const int cg   = wave & 1;          // col-group 0..1

    const int rowbase = blockIdx.x * BROWS + rg * 32;
    const int r0 = min(rowbase + lrow, M - 1);
    const int r1 = min(rowbase + 16 + lrow, M - 1);
    const int kq = quad * 8;
    const int ctbase = cg * WCT;        // 0 or 8

    f32x4 acc[2][WCT];
    #pragma unroll
    for (int i = 0; i < 2; i++)
        #pragma unroll
        for (int j = 0; j < WCT; j++)
            acc[i][j] = (f32x4){0.f, 0.f, 0.f, 0.f};

    bf16x8 fr[2][4];                    // 2-deep A prefetch, parity-indexed (fully unrolled)

    // prologue (VMEM issue order: B[0] x4, A[0] x4, A[1] x4)
    stage_b_async(Bsw, &Bs[0][0], tid);
    load_afrag(agg2, r0, r1, 0 + kq, fr[0]);
    load_afrag(agg2, r0, r1, 32 + kq, fr[1]);

    #pragma unroll
    for (int ks = 0; ks < KSTEPS; ks++) {
        __builtin_amdgcn_sched_barrier(0);
        if (ks == KSTEPS - 1) {
            asm volatile("s_waitcnt vmcnt(0)" ::: "memory");   // B[15] is newest: full drain
        } else {
            asm volatile("s_waitcnt vmcnt(4)" ::: "memory");   // leave newest 4 (A[ks+1]) flying
        }
        __builtin_amdgcn_s_barrier();
        __builtin_amdgcn_sched_barrier(0);

        if (ks + 1 < KSTEPS)
            stage_b_async(Bsw + (size_t)(ks + 1) * SLICE, &Bs[(ks + 1) & 1][0], tid);
        __builtin_amdgcn_sched_barrier(0);

        const ushort_t* bp = &Bs[ks & 1][ctbase * 512 + lane * 8];
        #pragma unroll
        for (int j = 0; j < WCT; j++) {
            const bf16x8 bh = *(const bf16x8*)(bp + j * 512);
            const bf16x8 bl = *(const bf16x8*)(bp + 8192 + j * 512);
            acc[0][j] = MFMA16(fr[ks & 1][0], bh, acc[0][j], 0, 0, 0);
            acc[1][j] = MFMA16(fr[ks & 1][2], bh, acc[1][j], 0, 0, 0);
            acc[0][j] = MFMA16(fr[ks & 1][1], bh, acc[0][j], 0, 0, 0);
            acc[1][j] = MFMA16(fr[ks & 1][3], bh, acc[1][j], 0, 0, 0);
            acc[0][j] = MFMA16(fr[ks & 1][0], bl, acc[0][j], 0, 0, 0);
            acc[1][j] = MFMA16(fr[ks & 1][2], bl, acc[1][j], 0, 0, 0);
        }

        // A[ks+2] overwrites fr[ks&1] (WAR on the frags orders this after the MFMA burst;
        // it is then the newest vmcnt group flying across the next two barriers)
        if (ks + 2 < KSTEPS) {
            const int k2 = ks + 2;
            const ushort_t* ab = (k2 < 8) ? agg2 : xin2;
            const int kk = ((k2 < 8) ? k2 * 32 : (k2 - 8) * 32) + kq;
            load_afrag(ab, r0, r1, kk, fr[ks & 1]);
        }
    }

    // ---- epilogue: bias (+relu+split for layers 1-2, f32 for layer 3) ----
    // C layout: col=lane&15, row=quad*4+reg
    #pragma unroll
    for (int j = 0; j < WCT; j++) {
        const int col = (ctbase + j) * 16 + lrow;
        const float bv = bias[col];
        #pragma unroll
        for (int rt = 0; rt < 2; rt++) {
            const int row = rowbase + rt * 16 + quad * 4;
            #pragma unroll
            for (int r = 0; r < 4; r++) {
                if (row + r < M) {
                    float v = acc[rt][j][r] + bv;
                    if (out_split) {
                        v = fmaxf(v, 0.f);
                        unsigned u = __float_as_uint(v);
                        float lo = v - bflo(u);
                        ushort_t* o = (ushort_t*)outp + (size_t)(row + r) * 512 + col;
                        o[0]   = (ushort_t)(u >> 16);
                        o[256] = (ushort_t)(__float_as_uint(lo) >> 16);
                    } else {
                        ((float*)outp)[(size_t)(row + r) * DIM + col] = v;
                    }
                }
            }
        }
    }
}

extern "C" void kernel_launch(void* const* d_in, const int* in_sizes, int n_in,
                              void* d_out, int out_size, void* d_ws, size_t ws_size,
                              hipStream_t stream) {
    const int*   edge = (const int*)d_in[0];
    const int*   src  = edge;
    const int*   dst  = edge + NEDGE;
    const float* x    = (const float*)d_in[1];
    const float* Wl1  = (const float*)d_in[2];
    const float* Wr1  = (const float*)d_in[3];
    const float* b1   = (const float*)d_in[4];
    const float* Wl2  = (const float*)d_in[5];
    const float* Wr2  = (const float*)d_in[6];
    const float* b2   = (const float*)d_in[7];
    const float* Wl3  = (const float*)d_in[8];
    const float* Wr3  = (const float*)d_in[9];
    const float* b3   = (const float*)d_in[10];

    // workspace: agg2 (split-plane, N*512 ushorts = 102.4 MB) + CSR + Bsw  (~109 MB total)
    ushort_t* agg2      = (ushort_t*)d_ws;
    int*      cnt       = (int*)(agg2 + (size_t)NNODES * 512);
    int*      row_start = cnt + NNODES;
    int*      cursor    = row_start + NNODES;
    int*      partial   = cursor + NNODES;            // 512
    int*      esrc      = partial + 512;              // NEDGE
    ushort_t* Bsw       = (ushort_t*)(esrc + NEDGE);  // KSTEPS*SLICE ushorts (512 KB)

    // x2 / h1 / h2 all live in the d_out region (N*512 ushorts == N*256 f32 == out_size);
    // each GEMM rewrites it in-place (block-own rows), layer 3 leaves f32 output there.
    ushort_t* x2 = (ushort_t*)d_out;

    const int nScanBlocks = (NNODES + 255) / 256;

    // ---- CSR build (edge structure shared by all 3 layers) ----
    hipMemsetAsync(cnt, 0, NNODES * sizeof(int), stream);
    hipMemsetAsync(cursor, 0, NNODES * sizeof(int), stream);
    count_kernel<<<(NEDGE + 255) / 256, 256, 0, stream>>>(dst, cnt, NEDGE);
    scan1<<<nScanBlocks, 256, 0, stream>>>(cnt, partial, NNODES);
    scan2<<<1, 512, 0, stream>>>(partial, nScanBlocks);
    scan3<<<nScanBlocks, 256, 0, stream>>>(cnt, partial, row_start, NNODES);
    fill_csr<<<(NEDGE + 255) / 256, 256, 0, stream>>>(src, dst, row_start, cursor, esrc, NEDGE);

    split_x<<<(NNODES * 64 + 255) / 256, 256, 0, stream>>>(x, x2);

    const int aggBlocks  = (NNODES * 64 + 255) / 256;
    const int gemmBlocks = (NNODES + BROWS - 1) / BROWS;
    const int convBlocks = (256 * 512 + 255) / 256;

    // ---- layer 1 ----
    conv_weights<<<convBlocks, 256, 0, stream>>>(Wl1, Wr1, Bsw);
    aggregate2<<<aggBlocks, 256, 0, stream>>>(esrc, row_start, cnt, x2, agg2);
    sage_gemm_mfma<<<gemmBlocks, 512, 0, stream>>>(agg2, x2, Bsw, b1, (void*)x2, NNODES, 1);

    // ---- layer 2 ----
    conv_weights<<<convBlocks, 256, 0, stream>>>(Wl2, Wr2, Bsw);
    aggregate2<<<aggBlocks, 256, 0, stream>>>(esrc, row_start, cnt, x2, agg2);
    sage_gemm_mfma<<<gemmBlocks, 512, 0, stream>>>(agg2, x2, Bsw, b2, (void*)x2, NNODES, 1);

    // ---- layer 3 ----
    conv_weights<<<convBlocks, 256, 0, stream>>>(Wl3, Wr3, Bsw);
    aggregate2<<<aggBlocks, 256, 0, stream>>>(esrc, row_start, cnt, x2, agg2);
    sage_gemm_mfma<<<gemmBlocks, 512, 0, stream>>>(agg2, x2, Bsw, b3, d_out, NNODES, 0);
}